// Round 1
// baseline (617.050 us; speedup 1.0000x reference)
//
#include <hip/hip_runtime.h>

#define Bn 512
#define Ln 2048
#define Kn 19
#define NEGV (-1000.0f)
#define START_IDn 17
#define PAD_IDn 18

// ---------------------------------------------------------------------------
// Forward Viterbi: one wave (64 threads) per 2 batches. lane = (half, c) with
// c in [0,32); c<19 are real tags. DP vector lives in LDS (dp[half][0..18]),
// broadcast-read by all lanes each step, updated wave-synchronously (no
// barriers: same-wave DS ops are in-order). Exact op order matches reference:
// cand = DP[p] + T[c][p]  (single f32 add), best = max, new = best + emit,
// argmax = first index attaining best (jnp.argmax tie-break).
// ---------------------------------------------------------------------------
__global__ __launch_bounds__(64, 1) void crf_fwd(
    const float* __restrict__ P, const float* __restrict__ T,
    const int* __restrict__ mask, unsigned char* __restrict__ choice,
    float* __restrict__ dpfin, int* __restrict__ lens)
{
    const int lane = threadIdx.x;
    const int half = lane >> 5;
    const int c = lane & 31;
    const int b = blockIdx.x * 2 + half;
    const int cc = (c < Kn) ? c : (Kn - 1);

    // Per-lane T row (19 VGPRs)
    float Trow[Kn];
#pragma unroll
    for (int p = 0; p < Kn; ++p) Trow[p] = T[cc * Kn + p];

    // length = sum of mask row (contiguous-prefix mask). 32 lanes per half
    // cooperatively sum 2048 ints with int4 loads, butterfly all-reduce.
    const int* mrow = mask + (size_t)b * Ln;
    int sum = 0;
#pragma unroll
    for (int j = 0; j < Ln / 128; ++j) {
        int4 v = *(const int4*)(mrow + j * 128 + c * 4);
        sum += v.x + v.y + v.z + v.w;
    }
#pragma unroll
    for (int k = 1; k < 32; k <<= 1) sum += __shfl_xor(sum, k, 64);
    const int len = sum;                 // per-half value (all 32 lanes have it)
    if (c == 0) lens[b] = len;
    const int lenO = __shfl_xor(len, 32, 64);
    int maxlen = len > lenO ? len : lenO;
    int mlen = (maxlen + 7) & ~7;        // unroll-8 padded; <= 2048 always
    mlen = __builtin_amdgcn_readfirstlane(mlen);

    __shared__ float dp[2][32];
    float mydp = (c == START_IDn) ? 0.0f : NEGV;
    dp[half][c] = mydp;

    const float* prow = P + (size_t)b * Ln * Kn;
    unsigned char* crow = choice + (size_t)b * Ln * Kn;

    // rolling emission prefetch (depth 8, static register indices via unroll)
    float eb[8];
#pragma unroll
    for (int u = 0; u < 8; ++u) eb[u] = prow[u * Kn + cc];

    for (int t0 = 0; t0 < mlen; t0 += 8) {
#pragma unroll
        for (int u = 0; u < 8; ++u) {
            const int t = t0 + u;
            const float e = eb[u];

            const float* base = &dp[half][0];
            float4 q0 = *(const float4*)(base + 0);
            float4 q1 = *(const float4*)(base + 4);
            float4 q2 = *(const float4*)(base + 8);
            float4 q3 = *(const float4*)(base + 12);
            float2 q4 = *(const float2*)(base + 16);
            float d18 = base[18];

            float cand[Kn];
            cand[0]  = q0.x + Trow[0];  cand[1]  = q0.y + Trow[1];
            cand[2]  = q0.z + Trow[2];  cand[3]  = q0.w + Trow[3];
            cand[4]  = q1.x + Trow[4];  cand[5]  = q1.y + Trow[5];
            cand[6]  = q1.z + Trow[6];  cand[7]  = q1.w + Trow[7];
            cand[8]  = q2.x + Trow[8];  cand[9]  = q2.y + Trow[9];
            cand[10] = q2.z + Trow[10]; cand[11] = q2.w + Trow[11];
            cand[12] = q3.x + Trow[12]; cand[13] = q3.y + Trow[13];
            cand[14] = q3.z + Trow[14]; cand[15] = q3.w + Trow[15];
            cand[16] = q4.x + Trow[16]; cand[17] = q4.y + Trow[17];
            cand[18] = d18  + Trow[18];

            // max tree, depth 3 (compiler fuses pairs into v_max3_f32)
            float m0 = fmaxf(fmaxf(cand[0],  cand[1]),  cand[2]);
            float m1 = fmaxf(fmaxf(cand[3],  cand[4]),  cand[5]);
            float m2 = fmaxf(fmaxf(cand[6],  cand[7]),  cand[8]);
            float m3 = fmaxf(fmaxf(cand[9],  cand[10]), cand[11]);
            float m4 = fmaxf(fmaxf(cand[12], cand[13]), cand[14]);
            float m5 = fmaxf(fmaxf(cand[15], cand[16]), cand[17]);
            float n0 = fmaxf(fmaxf(m0, m1), m2);
            float n1 = fmaxf(fmaxf(m3, m4), cand[18]);
            float best = fmaxf(fmaxf(n0, n1), m5);

            // first-index argmax (exact equality vs best) — off critical path
            int arg = Kn - 1;
#pragma unroll
            for (int p = Kn - 2; p >= 0; --p)
                arg = (cand[p] == best) ? p : arg;

            // masked update; mask is contiguous prefix -> t<len compare
            float nd = best + e;
            mydp = (t < len) ? nd : mydp;
            dp[half][c] = mydp;               // wave-synchronous LDS update

            if (c < Kn) crow[t * Kn + c] = (unsigned char)arg;

            // prefetch emission for t+8 (clamped address; value unused past end)
            int tn = t + 8;
            int tcl = tn < Ln ? tn : Ln - 1;
            eb[u] = prow[tcl * Kn + cc];
        }
    }
    if (c < Kn) dpfin[b * Kn + c] = mydp;   // DP frozen beyond len == final DP
}

// ---------------------------------------------------------------------------
// Backtrace: one block per batch. Exact integer function-composition scan:
//   g_t(x) = choice[t][x];  S_t = g_t o S_{t+1} (identity for t >= len)
//   path[t] = S_{t+1}(last) for t < len, else -1.
// Phase 1: 16 chunks x 128 steps composed in-place in LDS; each chunk's 19
// tag-lanes live inside one wave (3 chunks/wave) -> no per-step barriers.
// Phase 2: 16-step sequential chunk-boundary chain (thread 0).
// Phase 3: fully parallel emission out[t] = comp[t+1][ vchain[(t+1)/128 + 1] ].
// ---------------------------------------------------------------------------
__global__ __launch_bounds__(384, 1) void crf_bwd(
    const float* __restrict__ T, const unsigned char* __restrict__ choice,
    const float* __restrict__ dpfin, const int* __restrict__ lens,
    int* __restrict__ out)
{
    __shared__ unsigned char comp[Ln * Kn];   // 38912 B
    __shared__ int vchain[17];
    __shared__ int s_last, s_len;

    const int b = blockIdx.x;
    const int tid = threadIdx.x;

    // load this batch's backpointers into LDS (rows >= len hold garbage,
    // discarded by the t<len guard below)
    {
        const int4* src = (const int4*)(choice + (size_t)b * Ln * Kn);
        int4* dst = (int4*)comp;
        for (int i = tid; i < (Ln * Kn) / 16; i += 384) dst[i] = src[i];
    }
    if (tid == 0) {
        s_len = lens[b];
        // last = argmax_c( DPfinal[c] + T[PAD][c] ), first-index tie-break
        float bestv = dpfin[b * Kn + 0] + T[PAD_IDn * Kn + 0];
        int bl = 0;
        for (int ci = 1; ci < Kn; ++ci) {
            float v = dpfin[b * Kn + ci] + T[PAD_IDn * Kn + ci];
            if (v > bestv) { bestv = v; bl = ci; }
        }
        s_last = bl;
    }
    __syncthreads();
    const int len = s_len;

    // Phase 1: suffix-compose within each chunk, in place.
    {
        const int wv = tid >> 6;
        const int lane = tid & 63;
        const int ch = wv * 3 + lane / Kn;
        const int c = lane % Kn;
        if (lane < 3 * Kn && ch < 16) {
            int cur = c;                       // identity
            const int tb = ch * 128 + 127;
            for (int i = 0; i < 128; ++i) {
                const int t = tb - i;
                int nv = comp[t * Kn + cur];   // read g_t (in-bounds always)
                cur = (t < len) ? nv : cur;    // g_t = id for t >= len
                comp[t * Kn + c] = cur;        // overwrite row t with C_[t,b)
            }
        }
    }
    __syncthreads();

    // Phase 2: chunk-boundary values v[ch] = S_{ch*128}(last)
    if (tid == 0) {
        int v = s_last;
        vchain[16] = v;
        for (int ch = 15; ch >= 0; --ch) {
            v = comp[ch * 128 * Kn + v];
            vchain[ch] = v;
        }
    }
    __syncthreads();

    // Phase 3: emit path
    const int last = s_last;
    int* orow = out + (size_t)b * Ln;
    for (int t = tid; t < Ln; t += 384) {
        int val;
        if (t >= len) {
            val = -1;
        } else if (t == Ln - 1) {
            val = last;                        // only reachable when len == L
        } else {
            const int tp = t + 1;
            const int vc = vchain[(tp >> 7) + 1];
            val = comp[tp * Kn + vc];
        }
        orow[t] = val;
    }
}

// ---------------------------------------------------------------------------
extern "C" void kernel_launch(void* const* d_in, const int* in_sizes, int n_in,
                              void* d_out, int out_size, void* d_ws, size_t ws_size,
                              hipStream_t stream)
{
    const float* P    = (const float*)d_in[0];
    const float* T    = (const float*)d_in[1];
    const int*   mask = (const int*)d_in[2];
    int* out = (int*)d_out;

    // workspace layout
    const size_t choice_bytes = (size_t)Bn * Ln * Kn;          // 19,922,944
    unsigned char* choice = (unsigned char*)d_ws;
    float* dpfin = (float*)((char*)d_ws + choice_bytes);       // 512*19*4
    int* lens = (int*)((char*)d_ws + choice_bytes + (size_t)Bn * Kn * 4);

    crf_fwd<<<Bn / 2, 64, 0, stream>>>(P, T, mask, choice, dpfin, lens);
    crf_bwd<<<Bn, 384, 0, stream>>>(T, choice, dpfin, lens, out);
}